// Round 8
// baseline (408.862 us; speedup 1.0000x reference)
//
#include <hip/hip_runtime.h>
#include <hip/hip_bf16.h>

#define BATCH 8192
#define DIM   1024
#define INV_TAU (1.0f / 0.07f)
#define TOPM 0.95f
#define BOTM 0.05f

#define BM 256
#define BN 256
#define BK 64
#define NT (DIM / BK)   // 16 K-tiles per output tile

typedef __attribute__((ext_vector_type(4))) float f32x4;
typedef __attribute__((ext_vector_type(8))) short bf16x8;

typedef __attribute__((address_space(3))) void       lds_void_t;
typedef const __attribute__((address_space(1))) void gbl_void_t;

__device__ inline void async_copy16(const void* g, void* l) {
    __builtin_amdgcn_global_load_lds((gbl_void_t*)g, (lds_void_t*)l, 16, 0, 0);
}

__device__ inline unsigned short f2bf(float f) {
    __hip_bfloat16 h = __float2bfloat16(f);
    return *reinterpret_cast<unsigned short*>(&h);
}

// ---------------------------------------------------------------------------
// Kernel 1: per-row L2 norms, exact fp32 pos, bf16 writes, zero-init S.
// ---------------------------------------------------------------------------
__global__ __launch_bounds__(256) void prep_kernel(
    const float* __restrict__ A, const float* __restrict__ B,
    unsigned short* __restrict__ An, unsigned short* __restrict__ Bn,
    float* __restrict__ pos, float* __restrict__ S)
{
    int row = blockIdx.x;
    int t = threadIdx.x;
    const float4* a4 = (const float4*)(A + (size_t)row * DIM);
    const float4* b4 = (const float4*)(B + (size_t)row * DIM);
    float4 av = a4[t];
    float4 bv = b4[t];
    float sa = av.x*av.x + av.y*av.y + av.z*av.z + av.w*av.w;
    float sb = bv.x*bv.x + bv.y*bv.y + bv.z*bv.z + bv.w*bv.w;
    float dp = av.x*bv.x + av.y*bv.y + av.z*bv.z + av.w*bv.w;
    #pragma unroll
    for (int d = 32; d > 0; d >>= 1) {
        sa += __shfl_down(sa, d);
        sb += __shfl_down(sb, d);
        dp += __shfl_down(dp, d);
    }
    __shared__ float red[3][4];
    int lane = t & 63, w = t >> 6;
    if (lane == 0) { red[0][w] = sa; red[1][w] = sb; red[2][w] = dp; }
    __syncthreads();
    sa = red[0][0] + red[0][1] + red[0][2] + red[0][3];
    sb = red[1][0] + red[1][1] + red[1][2] + red[1][3];
    dp = red[2][0] + red[2][1] + red[2][2] + red[2][3];
    float ra = rsqrtf(sa);
    float rb = rsqrtf(sb);
    if (t == 0) {
        pos[row] = dp * ra * rb;
        S[row] = 0.0f;
    }
    ushort4 oa, ob;
    oa.x = f2bf(av.x * ra); oa.y = f2bf(av.y * ra);
    oa.z = f2bf(av.z * ra); oa.w = f2bf(av.w * ra);
    ob.x = f2bf(bv.x * rb); ob.y = f2bf(bv.y * rb);
    ob.z = f2bf(bv.z * rb); ob.w = f2bf(bv.w * rb);
    ((ushort4*)(An + (size_t)row * DIM))[t] = oa;
    ((ushort4*)(Bn + (size_t)row * DIM))[t] = ob;
}

// ---------------------------------------------------------------------------
// Kernel 2: PERSISTENT 256x256 MFMA GEMM + fused masked exp-sum.
// A operands: DIRECT global->register (16B/lane frags, 1-phase prefetch;
// the 4 waves sharing wm read the same 32KB panel in the same phase -> L1).
// B operands: staged LDS (2x32KB double buffer, both-sides XOR swizzle).
// LDS traffic per K-tile drops 192KB reads + 64KB writes -> 64KB + 32KB.
//
// VMEM issue order per K-tile t (p=t&1), groups pinned by SCH/memory-asm:
//  phY(t-1): [A-mh0(t) x8][stageB(t+1) x4]
//  phX(t):   BAR;SCH; ds b0,b1 (8 reads); [A-mh1(t) x8]; VMC(12)
//            -> drains A-mh0(t) (keeps stB(t+1)4 + A-mh1(t)8); MM(mh0xb0,b1)
//  phY(t):   BAR;SCH; [A-mh0(t+1) x8];SCH;[stageB(t+2) x4]; VMC(12)
//            -> drains stB(t+1)+A-mh1(t) (keeps A-mh0(t+1)8+stB(t+2)4);
//            MM(mh1xb1,b0)
// B-read safety: b reads of B(t+1) occur phX(t+1), after every wave drained
// stB(t+1) at its phY(t) VMC(12) and after BAR(phX(t+1)).
// B WAR: stage B(t+2)->buf p issued phY(t), after BAR following phX(t) where
// all waves' b-reads of buf p retired (compiler auto-waits before MFMAs).
// A-frag reads are C++ loads -> compiler inserts exact vmcnt waits too.
// Epilogue VMEM (pos loads, atomics) only over-drains later VMC(12): safe.
// ---------------------------------------------------------------------------
__global__ __launch_bounds__(512, 2) void sim_loss_kernel(
    const unsigned short* __restrict__ An, const unsigned short* __restrict__ Bn,
    const float* __restrict__ pos, float* __restrict__ S)
{
    __shared__ char lds[65536];   // B[2]: 0, 32768

    int tid  = threadIdx.x;
    int lane = tid & 63;
    int wave = tid >> 6;
    int wm = wave >> 2, wn = wave & 3;   // 2x4 wave grid, 128x64 per wave
    int fr = lane & 15;
    int q  = lane >> 4;

    int bid = blockIdx.x;   // 0..255

#define BASES(g, rB, cB) do {                                                        \
    int xcd_ = bid & 7, jj_ = bid >> 3;                                              \
    int qr_ = (g) >> 1, qc_ = ((g) & 1) ^ (qr_ & 1);                                 \
    (rB) = (qr_ * 16 + (xcd_ >> 1) * 4 + (jj_ >> 3)) * BM;                           \
    (cB) = (qc_ * 16 + (xcd_ & 1) * 8 + (jj_ & 7)) * BN;                             \
} while (0)

    f32x4 acc[8][4] = {};
    bf16x8 a0[4][2];     // mh0 fragments (prefetched 1 phase ahead)
    bf16x8 a1[4][2];     // mh1 fragments
    bf16x8 b0[2][2];     // nh0 fragments
    bf16x8 b1[2][2];     // nh1 fragments

    // B ds_read addressing (read-side swizzle)
    int sw = (fr & 7) << 4;
    int c0 = (q * 16) ^ sw;
    int c1 = (64 + q * 16) ^ sw;
    int bRow = (wn * 64 + fr) * 128;

    // B staging addressing (source-side swizzle, linear LDS dest)
    int strow = tid >> 3;                                  // 0..63
    int scb   = ((tid & 7) * 16) ^ ((strow & 7) << 4);
    int ldst = tid * 16;

#define BPANEL(cB, pB) do {                                                          \
    (pB) = (const char*)Bn + (size_t)((cB) + strow) * 2048 + scb;                    \
} while (0)
// A frag lane base: row = rowB + wm*128 + fr, col-bytes q*16
#define APANEL(rB, pA) do {                                                          \
    (pA) = (const char*)An + (size_t)((rB) + wm * 128 + fr) * 2048 + q * 16;         \
} while (0)

#define STAGE(gbase, u, h, ldsdst) do {                                              \
    async_copy16((gbase) + (size_t)(h) * 262144 + (size_t)(u) * 128,                 \
                 (ldsdst) + (h) * 16384 + ldst);                                     \
    async_copy16((gbase) + (size_t)(h) * 262144 + 131072 + (size_t)(u) * 128,        \
                 (ldsdst) + (h) * 16384 + 8192 + ldst);                              \
} while (0)

// A-frag global loads: arr[m][ks] = 16B at base + (mhrows + m*16)*2048 + ks*64
#define GLA(arr, base, mhrows) do {                                                  \
    _Pragma("unroll") for (int m = 0; m < 4; ++m) {                                  \
        arr[m][0] = *(const bf16x8*)((base) + (size_t)((mhrows) + m * 16) * 2048);   \
        arr[m][1] = *(const bf16x8*)((base) + (size_t)((mhrows) + m * 16) * 2048 + 64);\
    }                                                                                \
} while (0)

#define LDB_(arr, p, nh) do {                                                        \
    const char* _s = lds + (p) * 32768;                                              \
    _Pragma("unroll") for (int n = 0; n < 2; ++n) {                                  \
        arr[n][0] = *(const bf16x8*)(_s + bRow + (nh) * 4096 + n * 2048 + c0);       \
        arr[n][1] = *(const bf16x8*)(_s + bRow + (nh) * 4096 + n * 2048 + c1);       \
    }                                                                                \
} while (0)

#define MMA_(aarr, barr, mo, no) do {                                                \
    _Pragma("unroll") for (int m = 0; m < 4; ++m)                                    \
    _Pragma("unroll") for (int n = 0; n < 2; ++n) {                                  \
        acc[(mo)+m][(no)+n] = __builtin_amdgcn_mfma_f32_16x16x32_bf16(               \
            aarr[m][0], barr[n][0], acc[(mo)+m][(no)+n], 0, 0, 0);                   \
        acc[(mo)+m][(no)+n] = __builtin_amdgcn_mfma_f32_16x16x32_bf16(               \
            aarr[m][1], barr[n][1], acc[(mo)+m][(no)+n], 0, 0, 0);                   \
    }                                                                                \
} while (0)

#define BAR() __builtin_amdgcn_s_barrier()
#define SCH() __builtin_amdgcn_sched_barrier(0)
#define LGKM0() asm volatile("s_waitcnt lgkmcnt(0)" ::: "memory")
#define VMC(n)  asm volatile("s_waitcnt vmcnt(" #n ")" ::: "memory")
#define PRI1() __builtin_amdgcn_s_setprio(1)
#define PRI0() __builtin_amdgcn_s_setprio(0)

// pA1: lane base for this tile (mh1 = +64 rows); pA0: lane base for prefetch
// of next K-tile's mh0; pB_: B panel for stage of B(t+2) at slot uB.
#define KTILE(p, pA1, pA0, pB_, uB) do {                                             \
    char* stB = lds + (p) * 32768;                                                   \
    /* phX: quads (mh0,nh0),(mh0,nh1) */                                             \
    BAR(); SCH();                                                                    \
    LDB_(b0, (p), 0); LDB_(b1, (p), 1);                                              \
    GLA(a1, (pA1), 64);                                                              \
    VMC(12);                                                                         \
    PRI1(); MMA_(a0, b0, 0, 0); MMA_(a0, b1, 0, 2); PRI0();                          \
    LGKM0();                                                                         \
    /* phY: quads (mh1,nh1),(mh1,nh0) */                                             \
    BAR(); SCH();                                                                    \
    GLA(a0, (pA0), 0);                                                               \
    SCH();                                                                           \
    STAGE((pB_), (uB), 0, stB); STAGE((pB_), (uB), 1, stB);                          \
    VMC(12);                                                                         \
    PRI1(); MMA_(a1, b1, 4, 2); MMA_(a1, b0, 4, 0); PRI0();                          \
} while (0)

    int rowB, colB;
    BASES(0, rowB, colB);
    const char *gAf, *gBc;
    APANEL(rowB, gAf);
    BPANEL(colB, gBc);

    // Prologue: B(0)->buf0, B(1)->buf1; A-mh0(0) into a0; cold full drain.
    STAGE(gBc, 0, 0, lds);
    STAGE(gBc, 0, 1, lds);
    STAGE(gBc, 1, 0, lds + 32768);
    STAGE(gBc, 1, 1, lds + 32768);
    GLA(a0, gAf, 0);
    VMC(0);
    BAR();

    #pragma unroll 1
    for (int g = 0; g < 4; ++g) {
        int gn = (g < 3) ? g + 1 : 3;
        int rowBn, colBn;
        BASES(gn, rowBn, colBn);
        const char *gAfn, *gBn2;
        APANEL(rowBn, gAfn);
        BPANEL(colBn, gBn2);

        #pragma unroll 1
        for (int tt = 0; tt < 7; ++tt) {
            KTILE(0, gAf + (2 * tt) * 128,     gAf + (2 * tt + 1) * 128, gBc, 2 * tt + 2);
            KTILE(1, gAf + (2 * tt + 1) * 128, gAf + (2 * tt + 2) * 128, gBc, 2 * tt + 3);
        }
        // t=14: stage wraps to next tile's B(0); prefetch a0 of t=15.
        KTILE(0, gAf + 14 * 128, gAf + 15 * 128, gBn2, 0);
        // t=15: prefetch a0 of next gen's t=0; stage next gen's B(1).
        KTILE(1, gAf + 15 * 128, gAfn, gBn2, 1);

        // Epilogue for tile g (next tile's a0 + B stages in flight).
        #pragma unroll
        for (int m = 0; m < 8; ++m) {
            #pragma unroll
            for (int j2 = 0; j2 < 4; ++j2) {
                int i = rowB + wm * 128 + m * 16 + q * 4 + j2;
                float p  = pos[i];
                float up = TOPM * p, lo = BOTM * p;
                float rs = 0.0f;
                #pragma unroll
                for (int n = 0; n < 4; ++n) {
                    float sv = acc[m][n][j2];
                    int col = colB + wn * 64 + n * 16 + fr;
                    if (sv <= up && sv >= lo && col != i)
                        rs += __expf((sv - p) * INV_TAU);
                }
                #pragma unroll
                for (int d = 1; d < 16; d <<= 1)
                    rs += __shfl_xor(rs, d);
                if (fr == 0 && rs != 0.0f)
                    atomicAdd(&S[i], rs);
            }
        }
        #pragma unroll
        for (int m2 = 0; m2 < 8; ++m2)
            #pragma unroll
            for (int n2 = 0; n2 < 4; ++n2)
                acc[m2][n2] = (f32x4){0.0f, 0.0f, 0.0f, 0.0f};

        gAf = gAfn; gBc = gBn2; rowB = rowBn; colB = colBn;
    }
    LGKM0();
    VMC(0);    // drain redundant g=3 prefetch/staging + atomics before endpgm

#undef BASES
#undef BPANEL
#undef APANEL
#undef STAGE
#undef GLA
#undef LDB_
#undef MMA_
#undef BAR
#undef SCH
#undef LGKM0
#undef VMC
#undef PRI1
#undef PRI0
#undef KTILE
}

// ---------------------------------------------------------------------------
// Kernel 3: per_row = log1p(S_i) for rows with any negative; mean over valid.
// ---------------------------------------------------------------------------
__global__ __launch_bounds__(256) void finalize_kernel(
    const float* __restrict__ S, float* __restrict__ out)
{
    int t = threadIdx.x;
    float tot = 0.0f;
    int c = 0;
    for (int i = t; i < BATCH; i += 256) {
        float s = S[i];
        if (s > 0.0f) { tot += log1pf(s); c += 1; }
    }
    #pragma unroll
    for (int d = 32; d > 0; d >>= 1) {
        tot += __shfl_down(tot, d);
        c   += __shfl_down(c, d);
    }
    __shared__ float st[4];
    __shared__ int   sc[4];
    int lane = t & 63, w = t >> 6;
    if (lane == 0) { st[w] = tot; sc[w] = c; }
    __syncthreads();
    if (t == 0) {
        float T = st[0] + st[1] + st[2] + st[3];
        int   C = sc[0] + sc[1] + sc[2] + sc[3];
        out[0] = T / (float)(C > 0 ? C : 1);
    }
}

extern "C" void kernel_launch(void* const* d_in, const int* in_sizes, int n_in,
                              void* d_out, int out_size, void* d_ws, size_t ws_size,
                              hipStream_t stream) {
    const float* A = (const float*)d_in[0];
    const float* B = (const float*)d_in[1];

    char* ws = (char*)d_ws;
    unsigned short* An = (unsigned short*)ws;
    unsigned short* Bn = An + (size_t)BATCH * DIM;
    float* pos = (float*)(Bn + (size_t)BATCH * DIM);
    float* S   = pos + BATCH;
    float* out = (float*)d_out;

    prep_kernel<<<BATCH, 256, 0, stream>>>(A, B, An, Bn, pos, S);
    sim_loss_kernel<<<256, 512, 0, stream>>>(An, Bn, pos, S);
    finalize_kernel<<<1, 256, 0, stream>>>(S, out);
}

// Round 9
// 276.432 us; speedup vs baseline: 1.4791x; 1.4791x over previous
//
#include <hip/hip_runtime.h>
#include <hip/hip_bf16.h>

#define BATCH 8192
#define DIM   1024
#define INV_TAU (1.0f / 0.07f)
#define TOPM 0.95f
#define BOTM 0.05f

#define BM 128
#define BN 128
#define BK 64
#define NT (DIM / BK)   // 16 K-tiles per output tile

typedef __attribute__((ext_vector_type(4))) float f32x4;
typedef __attribute__((ext_vector_type(8))) short bf16x8;

typedef __attribute__((address_space(3))) void       lds_void_t;
typedef const __attribute__((address_space(1))) void gbl_void_t;

__device__ inline void async_copy16(const void* g, void* l) {
    __builtin_amdgcn_global_load_lds((gbl_void_t*)g, (lds_void_t*)l, 16, 0, 0);
}

__device__ inline unsigned short f2bf(float f) {
    __hip_bfloat16 h = __float2bfloat16(f);
    return *reinterpret_cast<unsigned short*>(&h);
}

// ---------------------------------------------------------------------------
// Kernel 1: per-row L2 norms, exact fp32 pos, bf16 writes, zero-init S.
// ---------------------------------------------------------------------------
__global__ __launch_bounds__(256) void prep_kernel(
    const float* __restrict__ A, const float* __restrict__ B,
    unsigned short* __restrict__ An, unsigned short* __restrict__ Bn,
    float* __restrict__ pos, float* __restrict__ S)
{
    int row = blockIdx.x;
    int t = threadIdx.x;
    const float4* a4 = (const float4*)(A + (size_t)row * DIM);
    const float4* b4 = (const float4*)(B + (size_t)row * DIM);
    float4 av = a4[t];
    float4 bv = b4[t];
    float sa = av.x*av.x + av.y*av.y + av.z*av.z + av.w*av.w;
    float sb = bv.x*bv.x + bv.y*bv.y + bv.z*bv.z + bv.w*bv.w;
    float dp = av.x*bv.x + av.y*bv.y + av.z*bv.z + av.w*bv.w;
    #pragma unroll
    for (int d = 32; d > 0; d >>= 1) {
        sa += __shfl_down(sa, d);
        sb += __shfl_down(sb, d);
        dp += __shfl_down(dp, d);
    }
    __shared__ float red[3][4];
    int lane = t & 63, w = t >> 6;
    if (lane == 0) { red[0][w] = sa; red[1][w] = sb; red[2][w] = dp; }
    __syncthreads();
    sa = red[0][0] + red[0][1] + red[0][2] + red[0][3];
    sb = red[1][0] + red[1][1] + red[1][2] + red[1][3];
    dp = red[2][0] + red[2][1] + red[2][2] + red[2][3];
    float ra = rsqrtf(sa);
    float rb = rsqrtf(sb);
    if (t == 0) {
        pos[row] = dp * ra * rb;
        S[row] = 0.0f;
    }
    ushort4 oa, ob;
    oa.x = f2bf(av.x * ra); oa.y = f2bf(av.y * ra);
    oa.z = f2bf(av.z * ra); oa.w = f2bf(av.w * ra);
    ob.x = f2bf(bv.x * rb); ob.y = f2bf(bv.y * rb);
    ob.z = f2bf(bv.z * rb); ob.w = f2bf(bv.w * rb);
    ((ushort4*)(An + (size_t)row * DIM))[t] = oa;
    ((ushort4*)(Bn + (size_t)row * DIM))[t] = ob;
}

// ---------------------------------------------------------------------------
// Kernel 2: 128x128-tile MFMA GEMM + fused masked exp-sum, sized for
// 2 BLOCKS / CU (64 KB LDS, <=128 VGPR, 8 waves of 64x32 output each).
// Cross-block wave overlap (m97/m114 mechanism) hides each block's
// lgkm/barrier/stage tails in the other block's MFMA phases.
//
// Per K-tile t (p=t&1; read A[p],B[p]; 2 barriers):
//  BAR1;SCH; ds a(8),b0(2),b1(2); stage A(t+1)->A[p^1] (2 vm);
//            MM(a,b0) 8 MFMA (compiler-gated); LGKM0 (my reads retired)
//  BAR2;SCH; (all waves' B[p] reads retired) stage B(t+2)->B[p] (2 vm);
//            MM(a,b1) 8 MFMA; VMC(2)
// vmcnt ledger at VMC(2): [B(t+1):2][A(t+1):2][B(t+2):2]=6 -> drains
//  B(t+1)+A(t+1), keeps B(t+2).  Next tile reads A(t+1)/B(t+1) after BAR1.
// A WAR: stage A[p^1]@BAR1(t): its reads (tile t-1) retired before
//  LGKM0(t-1) < BAR2(t-1) < BAR1(t).  B WAR: stage B[p]@after BAR2.
// u-slots wrap mod 16 in the last 2 tiles (redundant same-panel restage,
// ledger unchanged, harmless).  Final LGKM0+VMC(0) before endpgm.
//
// Block mapping: xcd = bid&7 owns a fixed 8-tile column band (B panel 2MB
// stays in its L2); generations g walk A row-bands shared by all XCDs (L3).
// ---------------------------------------------------------------------------
__global__ __launch_bounds__(512, 4) void sim_loss_kernel(
    const unsigned short* __restrict__ An, const unsigned short* __restrict__ Bn,
    const float* __restrict__ pos, float* __restrict__ S)
{
    __shared__ char lds[65536];   // A[2]: 0,16384 ; B[2]: 32768,49152

    int tid  = threadIdx.x;
    int lane = tid & 63;
    int wave = tid >> 6;
    int wm = wave >> 2, wn = wave & 3;   // 2x4 wave grid, 64x32 per wave
    int fr = lane & 15;
    int q  = lane >> 4;

    // bid -> (by,bx): xcd column bands + generation row bands
    int bid = blockIdx.x;               // 0..4095
    int xcd = bid & 7;
    int s   = bid >> 3;                 // 0..511
    int g   = s >> 6;                   // 0..7  (A row-band generation)
    int t5  = s & 63;
    int by  = g * 8 + (t5 >> 3);
    int bx  = xcd * 8 + (t5 & 7);
    int rowB = by * BM, colB = bx * BN;

    f32x4 acc[4][2] = {};
    bf16x8 a[4][2];      // 4 m-frags x 2 k-slices
    bf16x8 b0[2];        // nh0: [ks]
    bf16x8 b1[2];        // nh1: [ks]

    // ds_read addressing (read-side swizzle)
    int sw = (fr & 7) << 4;
    int c0 = (q * 16) ^ sw;
    int c1 = (64 + q * 16) ^ sw;
    int aRow = (wm * 64 + fr) * 128;
    int bRow = (wn * 32 + fr) * 128;

    // staging addressing (source-side swizzle, linear LDS dest)
    int strow = tid >> 3;                                  // 0..63
    int scb   = ((tid & 7) * 16) ^ ((strow & 7) << 4);
    int ldst = tid * 16;

    const char* gA = (const char*)An + (size_t)(rowB + strow) * 2048 + scb;
    const char* gB = (const char*)Bn + (size_t)(colB + strow) * 2048 + scb;

// one 16KB tile = 2 x 8KB issues (rows 0-63, 64-127); u = K-slot (128B)
#define STAGE(gbase, u, ldsdst) do {                                                 \
    async_copy16((gbase) + (size_t)(u) * 128, (ldsdst) + ldst);                      \
    async_copy16((gbase) + 131072 + (size_t)(u) * 128, (ldsdst) + 8192 + ldst);      \
} while (0)

#define LDA_(p) do {                                                                 \
    const char* _s = lds + (p) * 16384;                                              \
    _Pragma("unroll") for (int m = 0; m < 4; ++m) {                                  \
        a[m][0] = *(const bf16x8*)(_s + aRow + m * 2048 + c0);                       \
        a[m][1] = *(const bf16x8*)(_s + aRow + m * 2048 + c1);                       \
    }                                                                                \
} while (0)

#define LDB_(arr, p, nh) do {                                                        \
    const char* _s = lds + 32768 + (p) * 16384;                                      \
    arr[0] = *(const bf16x8*)(_s + bRow + (nh) * 2048 + c0);                         \
    arr[1] = *(const bf16x8*)(_s + bRow + (nh) * 2048 + c1);                         \
} while (0)

#define MM_(barr, no) do {                                                           \
    _Pragma("unroll") for (int m = 0; m < 4; ++m) {                                  \
        acc[m][no] = __builtin_amdgcn_mfma_f32_16x16x32_bf16(                        \
            a[m][0], barr[0], acc[m][no], 0, 0, 0);                                  \
        acc[m][no] = __builtin_amdgcn_mfma_f32_16x16x32_bf16(                        \
            a[m][1], barr[1], acc[m][no], 0, 0, 0);                                  \
    }                                                                                \
} while (0)

#define BAR() __builtin_amdgcn_s_barrier()
#define SCH() __builtin_amdgcn_sched_barrier(0)
#define LGKM0() asm volatile("s_waitcnt lgkmcnt(0)" ::: "memory")
#define VMC(n)  asm volatile("s_waitcnt vmcnt(" #n ")" ::: "memory")
#define PRI1() __builtin_amdgcn_s_setprio(1)
#define PRI0() __builtin_amdgcn_s_setprio(0)

#define KTILE(p, uA, uB) do {                                                        \
    char* stA = lds + ((p) ^ 1) * 16384;                                             \
    char* stB = lds + 32768 + (p) * 16384;                                           \
    BAR(); SCH();                                                                    \
    LDA_((p)); LDB_(b0, (p), 0); LDB_(b1, (p), 1);                                   \
    STAGE(gA, (uA), stA);                                                            \
    PRI1(); MM_(b0, 0); PRI0();                                                      \
    LGKM0();                                                                         \
    BAR(); SCH();                                                                    \
    STAGE(gB, (uB), stB);                                                            \
    PRI1(); MM_(b1, 1); PRI0();                                                      \
    VMC(2);                                                                          \
} while (0)

    // Prologue: A(0)->A[0], B(0)->B[0], B(1)->B[1]; drain A(0)+B(0), keep B(1).
    STAGE(gA, 0, lds);
    STAGE(gB, 0, lds + 32768);
    STAGE(gB, 1, lds + 49152);
    VMC(2);

    #pragma unroll 1
    for (int tt = 0; tt < 8; ++tt) {
        int t0 = 2 * tt;
        KTILE(0, (t0 + 1) & 15, (t0 + 2) & 15);
        KTILE(1, (t0 + 2) & 15, (t0 + 3) & 15);
    }

    // Epilogue: C/D map col=fr, row=q*4+j.  Validity == (S[i]>0) downstream.
    #pragma unroll
    for (int m = 0; m < 4; ++m) {
        #pragma unroll
        for (int j2 = 0; j2 < 4; ++j2) {
            int i = rowB + wm * 64 + m * 16 + q * 4 + j2;
            float p  = pos[i];
            float up = TOPM * p, lo = BOTM * p;
            float rs = 0.0f;
            #pragma unroll
            for (int n = 0; n < 2; ++n) {
                float sv = acc[m][n][j2];
                int col = colB + wn * 32 + n * 16 + fr;
                if (sv <= up && sv >= lo && col != i)
                    rs += __expf((sv - p) * INV_TAU);
            }
            #pragma unroll
            for (int d = 1; d < 16; d <<= 1)
                rs += __shfl_xor(rs, d);
            if (fr == 0 && rs != 0.0f)
                atomicAdd(&S[i], rs);
        }
    }
    LGKM0();
    VMC(0);   // drain redundant wrapped stages + atomics before endpgm

#undef STAGE
#undef LDA_
#undef LDB_
#undef MM_
#undef BAR
#undef SCH
#undef LGKM0
#undef VMC
#undef PRI1
#undef PRI0
#undef KTILE
}

// ---------------------------------------------------------------------------
// Kernel 3: per_row = log1p(S_i) for rows with any negative; mean over valid.
// ---------------------------------------------------------------------------
__global__ __launch_bounds__(256) void finalize_kernel(
    const float* __restrict__ S, float* __restrict__ out)
{
    int t = threadIdx.x;
    float tot = 0.0f;
    int c = 0;
    for (int i = t; i < BATCH; i += 256) {
        float s = S[i];
        if (s > 0.0f) { tot += log1pf(s); c += 1; }
    }
    #pragma unroll
    for (int d = 32; d > 0; d >>= 1) {
        tot += __shfl_down(tot, d);
        c   += __shfl_down(c, d);
    }
    __shared__ float st[4];
    __shared__ int   sc[4];
    int lane = t & 63, w = t >> 6;
    if (lane == 0) { st[w] = tot; sc[w] = c; }
    __syncthreads();
    if (t == 0) {
        float T = st[0] + st[1] + st[2] + st[3];
        int   C = sc[0] + sc[1] + sc[2] + sc[3];
        out[0] = T / (float)(C > 0 ? C : 1);
    }
}

extern "C" void kernel_launch(void* const* d_in, const int* in_sizes, int n_in,
                              void* d_out, int out_size, void* d_ws, size_t ws_size,
                              hipStream_t stream) {
    const float* A = (const float*)d_in[0];
    const float* B = (const float*)d_in[1];

    char* ws = (char*)d_ws;
    unsigned short* An = (unsigned short*)ws;
    unsigned short* Bn = An + (size_t)BATCH * DIM;
    float* pos = (float*)(Bn + (size_t)BATCH * DIM);
    float* S   = pos + BATCH;
    float* out = (float*)d_out;

    prep_kernel<<<BATCH, 256, 0, stream>>>(A, B, An, Bn, pos, S);
    sim_loss_kernel<<<(BATCH / BM) * (BATCH / BN), 512, 0, stream>>>(An, Bn, pos, S);
    finalize_kernel<<<1, 256, 0, stream>>>(S, out);
}

// Round 10
// 224.360 us; speedup vs baseline: 1.8223x; 1.2321x over previous
//
#include <hip/hip_runtime.h>
#include <hip/hip_bf16.h>

#define BATCH 8192
#define DIM   1024
#define INV_TAU (1.0f / 0.07f)
#define TOPM 0.95f
#define BOTM 0.05f

#define BM 256
#define BN 256
#define BK 64
#define NT (DIM / BK)   // 16 K-tiles per output tile

typedef __attribute__((ext_vector_type(4))) float f32x4;
typedef __attribute__((ext_vector_type(8))) short bf16x8;

typedef __attribute__((address_space(3))) void       lds_void_t;
typedef const __attribute__((address_space(1))) void gbl_void_t;

__device__ inline void async_copy16(const void* g, void* l) {
    __builtin_amdgcn_global_load_lds((gbl_void_t*)g, (lds_void_t*)l, 16, 0, 0);
}

__device__ inline unsigned short f2bf(float f) {
    __hip_bfloat16 h = __float2bfloat16(f);
    return *reinterpret_cast<unsigned short*>(&h);
}

// ---------------------------------------------------------------------------
// Kernel 1: per-row L2 norms, exact fp32 pos, bf16 writes, zero-init S.
// ---------------------------------------------------------------------------
__global__ __launch_bounds__(256) void prep_kernel(
    const float* __restrict__ A, const float* __restrict__ B,
    unsigned short* __restrict__ An, unsigned short* __restrict__ Bn,
    float* __restrict__ pos, float* __restrict__ S)
{
    int row = blockIdx.x;
    int t = threadIdx.x;
    const float4* a4 = (const float4*)(A + (size_t)row * DIM);
    const float4* b4 = (const float4*)(B + (size_t)row * DIM);
    float4 av = a4[t];
    float4 bv = b4[t];
    float sa = av.x*av.x + av.y*av.y + av.z*av.z + av.w*av.w;
    float sb = bv.x*bv.x + bv.y*bv.y + bv.z*bv.z + bv.w*bv.w;
    float dp = av.x*bv.x + av.y*bv.y + av.z*bv.z + av.w*bv.w;
    #pragma unroll
    for (int d = 32; d > 0; d >>= 1) {
        sa += __shfl_down(sa, d);
        sb += __shfl_down(sb, d);
        dp += __shfl_down(dp, d);
    }
    __shared__ float red[3][4];
    int lane = t & 63, w = t >> 6;
    if (lane == 0) { red[0][w] = sa; red[1][w] = sb; red[2][w] = dp; }
    __syncthreads();
    sa = red[0][0] + red[0][1] + red[0][2] + red[0][3];
    sb = red[1][0] + red[1][1] + red[1][2] + red[1][3];
    dp = red[2][0] + red[2][1] + red[2][2] + red[2][3];
    float ra = rsqrtf(sa);
    float rb = rsqrtf(sb);
    if (t == 0) {
        pos[row] = dp * ra * rb;
        S[row] = 0.0f;
    }
    ushort4 oa, ob;
    oa.x = f2bf(av.x * ra); oa.y = f2bf(av.y * ra);
    oa.z = f2bf(av.z * ra); oa.w = f2bf(av.w * ra);
    ob.x = f2bf(bv.x * rb); ob.y = f2bf(bv.y * rb);
    ob.z = f2bf(bv.z * rb); ob.w = f2bf(bv.w * rb);
    ((ushort4*)(An + (size_t)row * DIM))[t] = oa;
    ((ushort4*)(Bn + (size_t)row * DIM))[t] = ob;
}

// ---------------------------------------------------------------------------
// Kernel 2: PERSISTENT 256x256 MFMA GEMM + fused masked exp-sum.
// FRONT-LOADED-READS 3-phase K-tile with DEEP staging lead:
// all LDS reads of tile t happen in P1/P2; after the P2 barrier A[p],B[p]
// are WAR-free, so P3 stages tile t+2 into the SAME-parity (just-freed)
// buffers.  One counted VMC(8) at end of P3 gates tile t+1's loads, which
// were issued in P3(t-1) -> ~3 phases (>=1200 cyc) of issue-to-gate slack
// (vs ~400 cyc in R3..R7 -- the de-facto drain-0 that capped MfmaUtil at 31%).
//
// Per K-tile t (p = t&1; tiles t, t+2 both use buffer parity p):
//  P1: BAR;SCH; ds a0(8),b0(4);            PRI1 MM(a0,b0) PRI0; LGKM0
//  P2: BAR;SCH; ds a1(8),b1(4);            PRI1 MM(a0,b1) PRI0; LGKM0
//  P3: BAR;SCH; stage A(t+2)(4),B(t+2)(4); PRI1 MM(a1,b1); MM(a1,b0) PRI0;
//      VMC(8)
// vmcnt ledger at VMC(8): outstanding = this P3's 8 -> drains tile t+1's 8
//  (issued P3(t-1)).  Next tile's reads follow the BAR after VMC.  OK.
// WAR: stages at P3(t) overwrite A[p]/B[p], whose ds reads (P1/P2 of t) were
//  drained by each wave's LGKM0 before the P2->P3 BAR.  OK.
// Epilogue VMEM sits between gens; later VMC(8) over-drains it (safe).
// ---------------------------------------------------------------------------
__global__ __launch_bounds__(512, 2) void sim_loss_kernel(
    const unsigned short* __restrict__ An, const unsigned short* __restrict__ Bn,
    const float* __restrict__ pos, float* __restrict__ S)
{
    __shared__ char lds[131072];   // A[2]: 0,32768 ; B[2]: 65536, 98304

    int tid  = threadIdx.x;
    int lane = tid & 63;
    int wave = tid >> 6;
    int wm = wave >> 2, wn = wave & 3;   // 2x4 wave grid, 128x64 per wave
    int fr = lane & 15;
    int q  = lane >> 4;

    int bid = blockIdx.x;   // 0..255

#define BASES(g, rB, cB) do {                                                        \
    int xcd_ = bid & 7, jj_ = bid >> 3;                                              \
    int qr_ = (g) >> 1, qc_ = ((g) & 1) ^ (qr_ & 1);                                 \
    (rB) = (qr_ * 16 + (xcd_ >> 1) * 4 + (jj_ >> 3)) * BM;                           \
    (cB) = (qc_ * 16 + (xcd_ & 1) * 8 + (jj_ & 7)) * BN;                             \
} while (0)

    f32x4 acc[8][4] = {};
    bf16x8 a0[4][2];     // mh0 fragments (read P1, used P1/P2)
    bf16x8 a1[4][2];     // mh1 fragments (read P2, used P3)
    bf16x8 b0[2][2];     // nh0 fragments (read P1, used P1/P3)
    bf16x8 b1[2][2];     // nh1 fragments (read P2, used P2/P3)

    // ds_read addressing (read-side swizzle)
    int sw = (fr & 7) << 4;
    int c0 = (q * 16) ^ sw;
    int c1 = (64 + q * 16) ^ sw;
    int aRow = (wm * 128 + fr) * 128;
    int bRow = (wn * 64 + fr) * 128;

    // staging addressing (source-side swizzle, linear LDS dest)
    int strow = tid >> 3;                                  // 0..63
    int scb   = ((tid & 7) * 16) ^ ((strow & 7) << 4);
    int ldst = tid * 16;

#define PANELS(rB, cB, pA, pB) do {                                                  \
    (pA) = (const char*)An + (size_t)((rB) + strow) * 2048 + scb;                    \
    (pB) = (const char*)Bn + (size_t)((cB) + strow) * 2048 + scb;                    \
} while (0)

#define STAGE(gbase, u, h, ldsdst) do {                                              \
    async_copy16((gbase) + (size_t)(h) * 262144 + (size_t)(u) * 128,                 \
                 (ldsdst) + (h) * 16384 + ldst);                                     \
    async_copy16((gbase) + (size_t)(h) * 262144 + 131072 + (size_t)(u) * 128,        \
                 (ldsdst) + (h) * 16384 + 8192 + ldst);                              \
} while (0)

#define LDA_(arr, p, mh) do {                                                        \
    const char* _s = lds + (p) * 32768;                                              \
    _Pragma("unroll") for (int m = 0; m < 4; ++m) {                                  \
        arr[m][0] = *(const bf16x8*)(_s + aRow + (mh) * 8192 + m * 2048 + c0);       \
        arr[m][1] = *(const bf16x8*)(_s + aRow + (mh) * 8192 + m * 2048 + c1);       \
    }                                                                                \
} while (0)

#define LDB_(arr, p, nh) do {                                                        \
    const char* _s = lds + 65536 + (p) * 32768;                                      \
    _Pragma("unroll") for (int n = 0; n < 2; ++n) {                                  \
        arr[n][0] = *(const bf16x8*)(_s + bRow + (nh) * 4096 + n * 2048 + c0);       \
        arr[n][1] = *(const bf16x8*)(_s + bRow + (nh) * 4096 + n * 2048 + c1);       \
    }                                                                                \
} while (0)

#define MMA_(aarr, barr, mo, no) do {                                                \
    _Pragma("unroll") for (int m = 0; m < 4; ++m)                                    \
    _Pragma("unroll") for (int n = 0; n < 2; ++n) {                                  \
        acc[(mo)+m][(no)+n] = __builtin_amdgcn_mfma_f32_16x16x32_bf16(               \
            aarr[m][0], barr[n][0], acc[(mo)+m][(no)+n], 0, 0, 0);                   \
        acc[(mo)+m][(no)+n] = __builtin_amdgcn_mfma_f32_16x16x32_bf16(               \
            aarr[m][1], barr[n][1], acc[(mo)+m][(no)+n], 0, 0, 0);                   \
    }                                                                                \
} while (0)

#define BAR() __builtin_amdgcn_s_barrier()
#define SCH() __builtin_amdgcn_sched_barrier(0)
#define LGKM0() asm volatile("s_waitcnt lgkmcnt(0)" ::: "memory")
#define VMC(n)  asm volatile("s_waitcnt vmcnt(" #n ")" ::: "memory")
#define PRI1() __builtin_amdgcn_s_setprio(1)
#define PRI0() __builtin_amdgcn_s_setprio(0)

// Stages target the SAME parity p (tile t+2); A[p]/B[p] freed after P2.
#define KTILE(p, pA_, uA, pB_, uB) do {                                              \
    char* stA = lds + (p) * 32768;                                                   \
    char* stB = lds + 65536 + (p) * 32768;                                           \
    /* P1 */ BAR(); SCH();                                                           \
    LDA_(a0, (p), 0); LDB_(b0, (p), 0);                                              \
    PRI1(); MMA_(a0, b0, 0, 0); PRI0();                                              \
    LGKM0();                                                                         \
    /* P2 */ BAR(); SCH();                                                           \
    LDA_(a1, (p), 1); LDB_(b1, (p), 1);                                              \
    PRI1(); MMA_(a0, b1, 0, 2); PRI0();                                              \
    LGKM0();                                                                         \
    /* P3 */ BAR(); SCH();                                                           \
    STAGE((pA_), (uA), 0, stA); STAGE((pA_), (uA), 1, stA);                          \
    STAGE((pB_), (uB), 0, stB); STAGE((pB_), (uB), 1, stB);                          \
    PRI1(); MMA_(a1, b1, 4, 2); MMA_(a1, b0, 4, 0); PRI0();                          \
    VMC(8);                                                                          \
} while (0)

    int rowB, colB;
    BASES(0, rowB, colB);
    const char *gAc, *gBc;
    PANELS(rowB, colB, gAc, gBc);

    // Prologue: A(0),B(0) -> parity 0; A(1),B(1) -> parity 1; full drain.
    STAGE(gAc, 0, 0, lds);
    STAGE(gAc, 0, 1, lds);
    STAGE(gBc, 0, 0, lds + 65536);
    STAGE(gBc, 0, 1, lds + 65536);
    STAGE(gAc, 1, 0, lds + 32768);
    STAGE(gAc, 1, 1, lds + 32768);
    STAGE(gBc, 1, 0, lds + 98304);
    STAGE(gBc, 1, 1, lds + 98304);
    VMC(0);

    #pragma unroll 1
    for (int g = 0; g < 4; ++g) {
        int gn = (g < 3) ? g + 1 : 3;
        int rowBn, colBn;
        BASES(gn, rowBn, colBn);
        const char *gAn2, *gBn2;
        PANELS(rowBn, colBn, gAn2, gBn2);

        #pragma unroll 1
        for (int tt = 0; tt < 7; ++tt) {
            KTILE(0, gAc, 2 * tt + 2, gBc, 2 * tt + 2);
            KTILE(1, gAc, 2 * tt + 3, gBc, 2 * tt + 3);
        }
        // t=14 stages next gen's tile 0; t=15 stages next gen's tile 1.
        KTILE(0, gAn2, 0, gBn2, 0);
        KTILE(1, gAn2, 1, gBn2, 1);

        // Epilogue for tile g (next gen's tiles 0,1 already in flight).
        #pragma unroll
        for (int m = 0; m < 8; ++m) {
            #pragma unroll
            for (int j2 = 0; j2 < 4; ++j2) {
                int i = rowB + wm * 128 + m * 16 + q * 4 + j2;
                float p  = pos[i];
                float up = TOPM * p, lo = BOTM * p;
                float rs = 0.0f;
                #pragma unroll
                for (int n = 0; n < 4; ++n) {
                    float sv = acc[m][n][j2];
                    int col = colB + wn * 64 + n * 16 + fr;
                    if (sv <= up && sv >= lo && col != i)
                        rs += __expf((sv - p) * INV_TAU);
                }
                #pragma unroll
                for (int d = 1; d < 16; d <<= 1)
                    rs += __shfl_xor(rs, d);
                if (fr == 0 && rs != 0.0f)
                    atomicAdd(&S[i], rs);
            }
        }
        #pragma unroll
        for (int m2 = 0; m2 < 8; ++m2)
            #pragma unroll
            for (int n2 = 0; n2 < 4; ++n2)
                acc[m2][n2] = (f32x4){0.0f, 0.0f, 0.0f, 0.0f};

        gAc = gAn2; gBc = gBn2; rowB = rowBn; colB = colBn;
    }
    LGKM0();
    VMC(0);    // drain redundant g=3 restages + atomics before endpgm

#undef BASES
#undef PANELS
#undef STAGE
#undef LDA_
#undef LDB_
#undef MMA_
#undef BAR
#undef SCH
#undef LGKM0
#undef VMC
#undef PRI1
#undef PRI0
#undef KTILE
}

// ---------------------------------------------------------------------------
// Kernel 3: per_row = log1p(S_i) for rows with any negative; mean over valid.
// ---------------------------------------------------------------------------
__global__ __launch_bounds__(256) void finalize_kernel(
    const float* __restrict__ S, float* __restrict__ out)
{
    int t = threadIdx.x;
    float tot = 0.0f;
    int c = 0;
    for (int i = t; i < BATCH; i += 256) {
        float s = S[i];
        if (s > 0.0f) { tot += log1pf(s); c += 1; }
    }
    #pragma unroll
    for (int d = 32; d > 0; d >>= 1) {
        tot += __shfl_down(tot, d);
        c   += __shfl_down(c, d);
    }
    __shared__ float st[4];
    __shared__ int   sc[4];
    int lane = t & 63, w = t >> 6;
    if (lane == 0) { st[w] = tot; sc[w] = c; }
    __syncthreads();
    if (t == 0) {
        float T = st[0] + st[1] + st[2] + st[3];
        int   C = sc[0] + sc[1] + sc[2] + sc[3];
        out[0] = T / (float)(C > 0 ? C : 1);
    }
}

extern "C" void kernel_launch(void* const* d_in, const int* in_sizes, int n_in,
                              void* d_out, int out_size, void* d_ws, size_t ws_size,
                              hipStream_t stream) {
    const float* A = (const float*)d_in[0];
    const float* B = (const float*)d_in[1];

    char* ws = (char*)d_ws;
    unsigned short* An = (unsigned short*)ws;
    unsigned short* Bn = An + (size_t)BATCH * DIM;
    float* pos = (float*)(Bn + (size_t)BATCH * DIM);
    float* S   = pos + BATCH;
    float* out = (float*)d_out;

    prep_kernel<<<BATCH, 256, 0, stream>>>(A, B, An, Bn, pos, S);
    sim_loss_kernel<<<256, 512, 0, stream>>>(An, Bn, pos, S);
    finalize_kernel<<<1, 256, 0, stream>>>(S, out);
}

// Round 11
// 216.573 us; speedup vs baseline: 1.8879x; 1.0360x over previous
//
#include <hip/hip_runtime.h>
#include <hip/hip_bf16.h>

#define BATCH 8192
#define DIM   1024
#define INV_TAU (1.0f / 0.07f)
#define TOPM 0.95f
#define BOTM 0.05f

#define BM 256
#define BN 256
#define BK 64
#define NT (DIM / BK)   // 16 K-tiles per output tile

typedef __attribute__((ext_vector_type(4))) float f32x4;
typedef __attribute__((ext_vector_type(8))) short bf16x8;

typedef __attribute__((address_space(3))) void       lds_void_t;
typedef const __attribute__((address_space(1))) void gbl_void_t;

__device__ inline void async_copy16(const void* g, void* l) {
    __builtin_amdgcn_global_load_lds((gbl_void_t*)g, (lds_void_t*)l, 16, 0, 0);
}

__device__ inline unsigned short f2bf(float f) {
    __hip_bfloat16 h = __float2bfloat16(f);
    return *reinterpret_cast<unsigned short*>(&h);
}

// ---------------------------------------------------------------------------
// Kernel 1: per-row L2 norms, exact fp32 pos, bf16 writes, zero-init S.
// ---------------------------------------------------------------------------
__global__ __launch_bounds__(256) void prep_kernel(
    const float* __restrict__ A, const float* __restrict__ B,
    unsigned short* __restrict__ An, unsigned short* __restrict__ Bn,
    float* __restrict__ pos, float* __restrict__ S)
{
    int row = blockIdx.x;
    int t = threadIdx.x;
    const float4* a4 = (const float4*)(A + (size_t)row * DIM);
    const float4* b4 = (const float4*)(B + (size_t)row * DIM);
    float4 av = a4[t];
    float4 bv = b4[t];
    float sa = av.x*av.x + av.y*av.y + av.z*av.z + av.w*av.w;
    float sb = bv.x*bv.x + bv.y*bv.y + bv.z*bv.z + bv.w*bv.w;
    float dp = av.x*bv.x + av.y*bv.y + av.z*bv.z + av.w*bv.w;
    #pragma unroll
    for (int d = 32; d > 0; d >>= 1) {
        sa += __shfl_down(sa, d);
        sb += __shfl_down(sb, d);
        dp += __shfl_down(dp, d);
    }
    __shared__ float red[3][4];
    int lane = t & 63, w = t >> 6;
    if (lane == 0) { red[0][w] = sa; red[1][w] = sb; red[2][w] = dp; }
    __syncthreads();
    sa = red[0][0] + red[0][1] + red[0][2] + red[0][3];
    sb = red[1][0] + red[1][1] + red[1][2] + red[1][3];
    dp = red[2][0] + red[2][1] + red[2][2] + red[2][3];
    float ra = rsqrtf(sa);
    float rb = rsqrtf(sb);
    if (t == 0) {
        pos[row] = dp * ra * rb;
        S[row] = 0.0f;
    }
    ushort4 oa, ob;
    oa.x = f2bf(av.x * ra); oa.y = f2bf(av.y * ra);
    oa.z = f2bf(av.z * ra); oa.w = f2bf(av.w * ra);
    ob.x = f2bf(bv.x * rb); ob.y = f2bf(bv.y * rb);
    ob.z = f2bf(bv.z * rb); ob.w = f2bf(bv.w * rb);
    ((ushort4*)(An + (size_t)row * DIM))[t] = oa;
    ((ushort4*)(Bn + (size_t)row * DIM))[t] = ob;
}

// ---------------------------------------------------------------------------
// Kernel 2: PERSISTENT 256x256 MFMA GEMM + fused masked exp-sum.
// IDENTICAL to round-7 soft-seam schedule EXCEPT __launch_bounds__(512, 1):
// occupancy is LDS-bound at 1 block/CU (2 waves/SIMD) regardless, and the
// old (512,2) forced a 256-reg/wave cap that spilled the K-loop (evidence:
// WRITE_SIZE ~15MB vs ~2MB legitimate; VALUBusy 23%).  (512,1) removes the
// cap at identical true occupancy -> no spills.
//
// Per K-tile t (p=t&1; read A[p],B[p]):
//  phX: BAR;SCH; ds a0(8),b0(4),b1(4); stage A(t+1)h0+h1 -> A[p^1];
//       MM00, MM01 (compiler-gated); LGKM0
//  phY: BAR;SCH; ds a1(8); stage B(t+2)h0+h1 -> B[p];
//       MM11, MM10; LGKM0; VMC(4)
// vmcnt ledger at VMC(4): [B(t+1)4][A(t+1)4][B(t+2)4]=12 -> drains
//  B(t+1)+A(t+1), leaves B(t+2). Tile t+1 phX reads A(t+1),B(t+1). OK.
// WAR: stage A[p^1]@phX: its last reads (tile t-1) drained by t-1's LGKM0s
//  before barriers. stage B[p]@phY: this tile's b0/b1 reads drained by phX
//  LGKM0 before BAR(phY). Epilogue VMEM is older than next staging ->
//  VMC(4) over-drains it (safe).
// ---------------------------------------------------------------------------
__global__ __launch_bounds__(512, 1) void sim_loss_kernel(
    const unsigned short* __restrict__ An, const unsigned short* __restrict__ Bn,
    const float* __restrict__ pos, float* __restrict__ S)
{
    __shared__ char lds[131072];   // A[2]: 0,32768 ; B[2]: 65536, 98304

    int tid  = threadIdx.x;
    int lane = tid & 63;
    int wave = tid >> 6;
    int wm = wave >> 2, wn = wave & 3;   // 2x4 wave grid, 128x64 per wave
    int fr = lane & 15;
    int q  = lane >> 4;

    int bid = blockIdx.x;   // 0..255

#define BASES(g, rB, cB) do {                                                        \
    int xcd_ = bid & 7, jj_ = bid >> 3;                                              \
    int qr_ = (g) >> 1, qc_ = ((g) & 1) ^ (qr_ & 1);                                 \
    (rB) = (qr_ * 16 + (xcd_ >> 1) * 4 + (jj_ >> 3)) * BM;                           \
    (cB) = (qc_ * 16 + (xcd_ & 1) * 8 + (jj_ & 7)) * BN;                             \
} while (0)

    f32x4 acc[8][4] = {};
    bf16x8 a[4][2];      // current mh half: 4 m-frags x 2 k-slices
    bf16x8 b0[2][2];     // nh0 fragments
    bf16x8 b1[2][2];     // nh1 fragments

    // ds_read addressing (read-side swizzle)
    int sw = (fr & 7) << 4;
    int c0 = (q * 16) ^ sw;
    int c1 = (64 + q * 16) ^ sw;
    int aRow = (wm * 128 + fr) * 128;
    int bRow = (wn * 64 + fr) * 128;

    // staging addressing (source-side swizzle, linear LDS dest)
    int strow = tid >> 3;                                  // 0..63
    int scb   = ((tid & 7) * 16) ^ ((strow & 7) << 4);
    int ldst = tid * 16;

#define PANELS(rB, cB, pA, pB) do {                                                  \
    (pA) = (const char*)An + (size_t)((rB) + strow) * 2048 + scb;                    \
    (pB) = (const char*)Bn + (size_t)((cB) + strow) * 2048 + scb;                    \
} while (0)

#define STAGE(gbase, u, h, ldsdst) do {                                              \
    async_copy16((gbase) + (size_t)(h) * 262144 + (size_t)(u) * 128,                 \
                 (ldsdst) + (h) * 16384 + ldst);                                     \
    async_copy16((gbase) + (size_t)(h) * 262144 + 131072 + (size_t)(u) * 128,        \
                 (ldsdst) + (h) * 16384 + 8192 + ldst);                              \
} while (0)

#define LDA_(p, mh) do {                                                             \
    const char* _s = lds + (p) * 32768;                                              \
    _Pragma("unroll") for (int m = 0; m < 4; ++m) {                                  \
        a[m][0] = *(const bf16x8*)(_s + aRow + (mh) * 8192 + m * 2048 + c0);         \
        a[m][1] = *(const bf16x8*)(_s + aRow + (mh) * 8192 + m * 2048 + c1);         \
    }                                                                                \
} while (0)

#define LDB_(arr, p, nh) do {                                                        \
    const char* _s = lds + 65536 + (p) * 32768;                                      \
    _Pragma("unroll") for (int n = 0; n < 2; ++n) {                                  \
        arr[n][0] = *(const bf16x8*)(_s + bRow + (nh) * 4096 + n * 2048 + c0);       \
        arr[n][1] = *(const bf16x8*)(_s + bRow + (nh) * 4096 + n * 2048 + c1);       \
    }                                                                                \
} while (0)

#define MM_(barr, mo, no) do {                                                       \
    _Pragma("unroll") for (int m = 0; m < 4; ++m)                                    \
    _Pragma("unroll") for (int n = 0; n < 2; ++n) {                                  \
        acc[(mo)+m][(no)+n] = __builtin_amdgcn_mfma_f32_16x16x32_bf16(               \
            a[m][0], barr[n][0], acc[(mo)+m][(no)+n], 0, 0, 0);                      \
        acc[(mo)+m][(no)+n] = __builtin_amdgcn_mfma_f32_16x16x32_bf16(               \
            a[m][1], barr[n][1], acc[(mo)+m][(no)+n], 0, 0, 0);                      \
    }                                                                                \
} while (0)

#define BAR() __builtin_amdgcn_s_barrier()
#define SCH() __builtin_amdgcn_sched_barrier(0)
#define LGKM0() asm volatile("s_waitcnt lgkmcnt(0)" ::: "memory")
#define VMC(n)  asm volatile("s_waitcnt vmcnt(" #n ")" ::: "memory")
#define PRI1() __builtin_amdgcn_s_setprio(1)
#define PRI0() __builtin_amdgcn_s_setprio(0)

#define KTILE(p, pA_, uA, pB_, uB) do {                                              \
    char* stA = lds + ((p) ^ 1) * 32768;                                             \
    char* stB = lds + 65536 + (p) * 32768;                                           \
    /* phX: quads (mh0,nh0),(mh0,nh1) */                                             \
    BAR(); SCH();                                                                    \
    LDA_((p), 0); LDB_(b0, (p), 0); LDB_(b1, (p), 1);                                \
    STAGE((pA_), (uA), 0, stA); STAGE((pA_), (uA), 1, stA);                          \
    PRI1(); MM_(b0, 0, 0); MM_(b1, 0, 2); PRI0();                                    \
    LGKM0();                                                                         \
    /* phY: quads (mh1,nh1),(mh1,nh0) */                                             \
    BAR(); SCH();                                                                    \
    LDA_((p), 1);                                                                    \
    STAGE((pB_), (uB), 0, stB); STAGE((pB_), (uB), 1, stB);                          \
    PRI1(); MM_(b1, 4, 2); MM_(b0, 4, 0); PRI0();                                    \
    LGKM0(); VMC(4);                                                                 \
} while (0)

    int rowB, colB;
    BASES(0, rowB, colB);
    const char *gAc, *gBc;
    PANELS(rowB, colB, gAc, gBc);

    // Prologue (once): A(0)->A[0], B(0)->B[0], B(1)->B[1]; drain to 4.
    STAGE(gAc, 0, 0, lds);
    STAGE(gAc, 0, 1, lds);
    STAGE(gBc, 0, 0, lds + 65536);
    STAGE(gBc, 0, 1, lds + 65536);
    STAGE(gBc, 1, 0, lds + 98304);
    STAGE(gBc, 1, 1, lds + 98304);
    VMC(4);

    #pragma unroll 1
    for (int g = 0; g < 4; ++g) {
        int gn = (g < 3) ? g + 1 : 3;
        int rowBn, colBn;
        BASES(gn, rowBn, colBn);
        const char *gAn2, *gBn2;
        PANELS(rowBn, colBn, gAn2, gBn2);

        #pragma unroll 1
        for (int tt = 0; tt < 7; ++tt) {
            KTILE(0, gAc, 2 * tt + 1, gBc, 2 * tt + 2);
            KTILE(1, gAc, 2 * tt + 2, gBc, 2 * tt + 3);
        }
        // t=14: A(15); B wraps to next tile's B(0).
        KTILE(0, gAc, 15, gBn2, 0);
        // t=15: A wraps to next A(0); B to next B(1).
        KTILE(1, gAn2, 0, gBn2, 1);

        // Epilogue for tile g (next tile's first operands already in flight).
        #pragma unroll
        for (int m = 0; m < 8; ++m) {
            #pragma unroll
            for (int j2 = 0; j2 < 4; ++j2) {
                int i = rowB + wm * 128 + m * 16 + q * 4 + j2;
                float p  = pos[i];
                float up = TOPM * p, lo = BOTM * p;
                float rs = 0.0f;
                #pragma unroll
                for (int n = 0; n < 4; ++n) {
                    float sv = acc[m][n][j2];
                    int col = colB + wn * 64 + n * 16 + fr;
                    if (sv <= up && sv >= lo && col != i)
                        rs += __expf((sv - p) * INV_TAU);
                }
                #pragma unroll
                for (int d = 1; d < 16; d <<= 1)
                    rs += __shfl_xor(rs, d);
                if (fr == 0 && rs != 0.0f)
                    atomicAdd(&S[i], rs);
            }
        }
        #pragma unroll
        for (int m2 = 0; m2 < 8; ++m2)
            #pragma unroll
            for (int n2 = 0; n2 < 4; ++n2)
                acc[m2][n2] = (f32x4){0.0f, 0.0f, 0.0f, 0.0f};

        gAc = gAn2; gBc = gBn2; rowB = rowBn; colB = colBn;
    }
    LGKM0();
    VMC(0);    // drain redundant g=3 staging + atomics before endpgm

#undef BASES
#undef PANELS
#undef STAGE
#undef LDA_
#undef LDB_
#undef MM_
#undef BAR
#undef SCH
#undef LGKM0
#undef VMC
#undef PRI1
#undef PRI0
#undef KTILE
}

// ---------------------------------------------------------------------------
// Kernel 3: per_row = log1p(S_i) for rows with any negative; mean over valid.
// ---------------------------------------------------------------------------
__global__ __launch_bounds__(256) void finalize_kernel(
    const float* __restrict__ S, float* __restrict__ out)
{
    int t = threadIdx.x;
    float tot = 0.0f;
    int c = 0;
    for (int i = t; i < BATCH; i += 256) {
        float s = S[i];
        if (s > 0.0f) { tot += log1pf(s); c += 1; }
    }
    #pragma unroll
    for (int d = 32; d > 0; d >>= 1) {
        tot += __shfl_down(tot, d);
        c   += __shfl_down(c, d);
    }
    __shared__ float st[4];
    __shared__ int   sc[4];
    int lane = t & 63, w = t >> 6;
    if (lane == 0) { st[w] = tot; sc[w] = c; }
    __syncthreads();
    if (t == 0) {
        float T = st[0] + st[1] + st[2] + st[3];
        int   C = sc[0] + sc[1] + sc[2] + sc[3];
        out[0] = T / (float)(C > 0 ? C : 1);
    }
}

extern "C" void kernel_launch(void* const* d_in, const int* in_sizes, int n_in,
                              void* d_out, int out_size, void* d_ws, size_t ws_size,
                              hipStream_t stream) {
    const float* A = (const float*)d_in[0];
    const float* B = (const float*)d_in[1];

    char* ws = (char*)d_ws;
    unsigned short* An = (unsigned short*)ws;
    unsigned short* Bn = An + (size_t)BATCH * DIM;
    float* pos = (float*)(Bn + (size_t)BATCH * DIM);
    float* S   = pos + BATCH;
    float* out = (float*)d_out;

    prep_kernel<<<BATCH, 256, 0, stream>>>(A, B, An, Bn, pos, S);
    sim_loss_kernel<<<256, 512, 0, stream>>>(An, Bn, pos, S);
    finalize_kernel<<<1, 256, 0, stream>>>(S, out);
}